// Round 4
// baseline (770.740 us; speedup 1.0000x reference)
//
#include <hip/hip_runtime.h>

#define D 256
#define KDIM 512
#define BCAP 16384  // per-bucket staging capacity (avg fill 8184 for E=3.2M, B1=391)
#define MTILE 128

typedef __bf16 bf16_t;
typedef bf16_t bf16x8 __attribute__((ext_vector_type(8)));
typedef bf16_t bf16x4 __attribute__((ext_vector_type(4)));
typedef float f32x4_t __attribute__((ext_vector_type(4)));
typedef float f32x2_t __attribute__((ext_vector_type(2)));

// ---------------- CSR build (bucketed, no global hist) ----------------

// pass 1: coarse scatter into 256-node buckets; packed word = (dst&255)<<24 | src
__global__ __launch_bounds__(256) void k_scatter1(const int* __restrict__ eidx,
                                                  int* __restrict__ bcur,
                                                  int* __restrict__ staging, int E) {
    int e = blockIdx.x * 256 + threadIdx.x;
    if (e >= E) return;
    int s = eidx[e];
    int d = eidx[E + e];
    int b = d >> 8;
    int pos = atomicAdd(&bcur[b * 16], 1);  // cursors padded 1/line
    staging[(size_t)b * BCAP + pos] = ((d & 255) << 24) | s;  // s < 2^24
}

// scan of bucket counts -> bucket base offsets (B1 <= 512)
__global__ __launch_bounds__(512) void k_bbase(const int* __restrict__ bcur,
                                               int* __restrict__ bbase,
                                               int* __restrict__ row_ptr,
                                               int B1, int N, int E) {
    __shared__ int sm[512];
    int t = threadIdx.x;
    int v = (t < B1) ? bcur[t * 16] : 0;
    sm[t] = v;
    __syncthreads();
    for (int off = 1; off < 512; off <<= 1) {
        int u = (t >= off) ? sm[t - off] : 0;
        __syncthreads();
        sm[t] += u;
        __syncthreads();
    }
    if (t < B1) bbase[t] = sm[t] - v;  // exclusive
    if (t == 0) row_ptr[N] = E;
}

// pass 2: per-bucket hist + scan + counting-sort; emits row_ptr AND edge_src
__global__ __launch_bounds__(256) void k_bucket(const int* __restrict__ bcur,
                                                const int* __restrict__ bbase,
                                                const int* __restrict__ staging,
                                                int* __restrict__ edge_src,
                                                int* __restrict__ row_ptr, int N) {
    __shared__ int lhist[256];
    __shared__ int lscan[256];
    __shared__ int lcur[256];
    int b = blockIdx.x, t = threadIdx.x;
    int node_base = b << 8;
    int nn = N - node_base;
    if (nn > 256) nn = 256;
    int cnt = bcur[b * 16];
    int base = bbase[b];
    const int* stg = staging + (size_t)b * BCAP;

    lhist[t] = 0;
    __syncthreads();
    for (int i = t; i < cnt; i += 256)
        atomicAdd(&lhist[((unsigned)stg[i]) >> 24], 1);
    __syncthreads();
    int v = lhist[t];
    lscan[t] = v;
    __syncthreads();
    for (int off = 1; off < 256; off <<= 1) {
        int u = (t >= off) ? lscan[t - off] : 0;
        __syncthreads();
        lscan[t] += u;
        __syncthreads();
    }
    int excl = lscan[t] - v;
    if (t < nn) row_ptr[node_base + t] = base + excl;
    lscan[t] = excl;
    lcur[t] = 0;
    __syncthreads();
    for (int i = t; i < cnt; i += 256) {
        int w = stg[i];
        int ln = ((unsigned)w) >> 24;
        int src = w & 0xFFFFFF;
        int pos = base + lscan[ln] + atomicAdd(&lcur[ln], 1);
        edge_src[pos] = src;
    }
}

// ---------------- conversions ----------------

// x (f32) -> Xq (fp8 e4m3, packed 4/dword) — gather table for aggregation
__global__ __launch_bounds__(256) void k_convx(const float* __restrict__ x,
                                               unsigned int* __restrict__ Xq,
                                               int total8) {
    int i = blockIdx.x * 256 + threadIdx.x;  // one thread = 8 elems
    if (i >= total8) return;
    float4 v0 = *(const float4*)(x + (size_t)i * 8);
    float4 v1 = *(const float4*)(x + (size_t)i * 8 + 4);
    int w0 = 0, w1 = 0;
    w0 = __builtin_amdgcn_cvt_pk_fp8_f32(v0.x, v0.y, w0, false);
    w0 = __builtin_amdgcn_cvt_pk_fp8_f32(v0.z, v0.w, w0, true);
    w1 = __builtin_amdgcn_cvt_pk_fp8_f32(v1.x, v1.y, w1, false);
    w1 = __builtin_amdgcn_cvt_pk_fp8_f32(v1.z, v1.w, w1, true);
    uint2 o = {(unsigned)w0, (unsigned)w1};
    *(uint2*)(Xq + (size_t)i * 2) = o;
}

// Wcat [256][512] bf16: [:,0:256]=W_l, [:,256:512]=W_r
__global__ __launch_bounds__(256) void k_convw(const float* __restrict__ Wl,
                                               const float* __restrict__ Wr,
                                               bf16_t* __restrict__ Wcat) {
    int i = blockIdx.x * 256 + threadIdx.x;
    if (i >= D * KDIM / 4) return;
    int o = i * 4;
    int j = o >> 9;
    int k = o & 511;
    const float* src = (k < D) ? (Wl + (size_t)j * D + k)
                               : (Wr + (size_t)j * D + (k - D));
    float4 v = *(const float4*)src;
    bf16x4 ov = {(bf16_t)v.x, (bf16_t)v.y, (bf16_t)v.z, (bf16_t)v.w};
    *(bf16x4*)(Wcat + o) = ov;
}

// ------- aggregation: one wave per node, 4 fp8 rows per load instruction ----

__global__ __launch_bounds__(256) void k_aggregate(const int* __restrict__ row_ptr,
                                                   const int* __restrict__ edge_src,
                                                   const unsigned int* __restrict__ Xq,
                                                   bf16_t* __restrict__ Agg, int N) {
    int wv = threadIdx.x >> 6;
    int lane = threadIdx.x & 63;
    int node = blockIdx.x * 4 + wv;
    if (node >= N) return;
    int g = lane >> 4;       // row group 0..3
    int c = lane & 15;       // 16-fp8 column chunk
    int beg = row_ptr[node];
    int end = row_ptr[node + 1];

    float acc[16];
#pragma unroll
    for (int k = 0; k < 16; k++) acc[k] = 0.f;

#define ACC4(w, bidx)                                            \
    {                                                            \
        f32x2_t lo = __builtin_amdgcn_cvt_pk_f32_fp8((w), false);\
        f32x2_t hi = __builtin_amdgcn_cvt_pk_f32_fp8((w), true); \
        acc[(bidx) + 0] += lo[0];                                \
        acc[(bidx) + 1] += lo[1];                                \
        acc[(bidx) + 2] += hi[0];                                \
        acc[(bidx) + 3] += hi[1];                                \
    }

    for (int j = beg; j < end; j += 8) {
        int j0 = j + g, j1 = j + 4 + g;
        bool ok0 = j0 < end, ok1 = j1 < end;
        int s0 = edge_src[ok0 ? j0 : beg];
        int s1 = edge_src[ok1 ? j1 : beg];
        uint4 v0 = *(const uint4*)(Xq + (size_t)s0 * 64 + c * 4);
        uint4 v1 = *(const uint4*)(Xq + (size_t)s1 * 64 + c * 4);
        if (!ok0) { v0.x = 0; v0.y = 0; v0.z = 0; v0.w = 0; }
        if (!ok1) { v1.x = 0; v1.y = 0; v1.z = 0; v1.w = 0; }
        ACC4(v0.x, 0) ACC4(v0.y, 4) ACC4(v0.z, 8) ACC4(v0.w, 12)
        ACC4(v1.x, 0) ACC4(v1.y, 4) ACC4(v1.z, 8) ACC4(v1.w, 12)
    }
#undef ACC4

    // combine the 4 row-groups: lanes g*16+c all hold partial sums of chunk c
#pragma unroll
    for (int k = 0; k < 16; k++) {
        acc[k] += __shfl_xor(acc[k], 16, 64);
        acc[k] += __shfl_xor(acc[k], 32, 64);
    }
    int dg = end - beg;
    float inv = 1.0f / (float)(dg > 0 ? dg : 1);
    if (g == 0) {  // lanes 0..15 write 32B each = full 512B row
        bf16x8 o0 = {(bf16_t)(acc[0] * inv), (bf16_t)(acc[1] * inv),
                     (bf16_t)(acc[2] * inv), (bf16_t)(acc[3] * inv),
                     (bf16_t)(acc[4] * inv), (bf16_t)(acc[5] * inv),
                     (bf16_t)(acc[6] * inv), (bf16_t)(acc[7] * inv)};
        bf16x8 o1 = {(bf16_t)(acc[8] * inv), (bf16_t)(acc[9] * inv),
                     (bf16_t)(acc[10] * inv), (bf16_t)(acc[11] * inv),
                     (bf16_t)(acc[12] * inv), (bf16_t)(acc[13] * inv),
                     (bf16_t)(acc[14] * inv), (bf16_t)(acc[15] * inv)};
        *(bf16x8*)(Agg + (size_t)node * D + c * 16) = o0;
        *(bf16x8*)(Agg + (size_t)node * D + c * 16 + 8) = o1;
    }
}

// ------- GEMM (K=512 concat) fused with bias+GELU+LayerNorm+residual -------
// Block: 128 rows x 256 cols; 4 waves, each owns 128-row x 64-col strip.

__global__ __launch_bounds__(256) void k_gemm(const bf16_t* __restrict__ Agg,
                                              const bf16_t* __restrict__ Wcat,
                                              const float* __restrict__ x,
                                              const float* __restrict__ b_l,
                                              const float* __restrict__ gamma,
                                              const float* __restrict__ beta,
                                              float* __restrict__ out, int M) {
    int wid = threadIdx.x >> 6;
    int lane = threadIdx.x & 63;
    int lr = lane & 15;
    int lh = lane >> 4;
    int row0 = blockIdx.x * MTILE;

    f32x4_t acc[8][4];
#pragma unroll
    for (int i = 0; i < 8; i++)
#pragma unroll
        for (int j = 0; j < 4; j++) acc[i][j] = (f32x4_t){0.f, 0.f, 0.f, 0.f};

    int rown[8];
#pragma unroll
    for (int mt = 0; mt < 8; mt++) {
        int r = row0 + mt * 16 + lr;
        rown[mt] = (r > M - 1) ? (M - 1) : r;
    }

    // K half 1: Agg (bf16) x W_l
#pragma unroll 2
    for (int k0 = 0; k0 < 256; k0 += 32) {
        int kk = k0 + lh * 8;
        bf16x8 a[8], b[4];
#pragma unroll
        for (int mt = 0; mt < 8; mt++)
            a[mt] = *(const bf16x8*)(Agg + (size_t)rown[mt] * D + kk);
#pragma unroll
        for (int nt = 0; nt < 4; nt++) {
            int c = wid * 64 + nt * 16 + lr;
            b[nt] = *(const bf16x8*)(Wcat + (size_t)c * KDIM + kk);
        }
#pragma unroll
        for (int mt = 0; mt < 8; mt++)
#pragma unroll
            for (int nt = 0; nt < 4; nt++)
                acc[mt][nt] = __builtin_amdgcn_mfma_f32_16x16x32_bf16(
                    a[mt], b[nt], acc[mt][nt], 0, 0, 0);
    }
    // K half 2: x (f32 -> bf16 on the fly) x W_r
#pragma unroll 2
    for (int k0 = 0; k0 < 256; k0 += 32) {
        int kk = k0 + lh * 8;
        bf16x8 a[8], b[4];
#pragma unroll
        for (int mt = 0; mt < 8; mt++) {
            float4 u0 = *(const float4*)(x + (size_t)rown[mt] * D + kk);
            float4 u1 = *(const float4*)(x + (size_t)rown[mt] * D + kk + 4);
            a[mt] = (bf16x8){(bf16_t)u0.x, (bf16_t)u0.y, (bf16_t)u0.z, (bf16_t)u0.w,
                             (bf16_t)u1.x, (bf16_t)u1.y, (bf16_t)u1.z, (bf16_t)u1.w};
        }
#pragma unroll
        for (int nt = 0; nt < 4; nt++) {
            int c = wid * 64 + nt * 16 + lr;
            b[nt] = *(const bf16x8*)(Wcat + (size_t)c * KDIM + 256 + kk);
        }
#pragma unroll
        for (int mt = 0; mt < 8; mt++)
#pragma unroll
            for (int nt = 0; nt < 4; nt++)
                acc[mt][nt] = __builtin_amdgcn_mfma_f32_16x16x32_bf16(
                    a[mt], b[nt], acc[mt][nt], 0, 0, 0);
    }

    // ---- fused epilogue: bias + exact GELU + LayerNorm + residual ----
    __shared__ float sm_s[4][MTILE];
    __shared__ float sm_q[4][MTILE];

    float bl[4], ga[4], be[4];
#pragma unroll
    for (int nt = 0; nt < 4; nt++) {
        int c = wid * 64 + nt * 16 + lr;
        bl[nt] = b_l[c];
        ga[nt] = gamma[c];
        be[nt] = beta[c];
    }

#pragma unroll
    for (int mt = 0; mt < 8; mt++) {
#pragma unroll
        for (int r = 0; r < 4; r++) {
            float s = 0.f, q = 0.f;
#pragma unroll
            for (int nt = 0; nt < 4; nt++) {
                float u = acc[mt][nt][r] + bl[nt];
                float ge = 0.5f * u * (1.0f + erff(u * 0.70710678118654752f));
                acc[mt][nt][r] = ge;
                s += ge;
                q += ge * ge;
            }
#pragma unroll
            for (int off = 8; off >= 1; off >>= 1) {
                s += __shfl_xor(s, off, 64);
                q += __shfl_xor(q, off, 64);
            }
            if (lr == 0) {
                int rl = mt * 16 + lh * 4 + r;
                sm_s[wid][rl] = s;
                sm_q[wid][rl] = q;
            }
        }
    }
    __syncthreads();

#pragma unroll
    for (int mt = 0; mt < 8; mt++) {
#pragma unroll
        for (int r = 0; r < 4; r++) {
            int rl = mt * 16 + lh * 4 + r;
            int m = row0 + rl;
            float S = sm_s[0][rl] + sm_s[1][rl] + sm_s[2][rl] + sm_s[3][rl];
            float Q = sm_q[0][rl] + sm_q[1][rl] + sm_q[2][rl] + sm_q[3][rl];
            float mean = S * (1.0f / 256.0f);
            float var = Q * (1.0f / 256.0f) - mean * mean;
            float rstd = rsqrtf(var + 1e-5f);
            if (m < M) {
#pragma unroll
                for (int nt = 0; nt < 4; nt++) {
                    int c = wid * 64 + nt * 16 + lr;
                    out[(size_t)m * D + c] =
                        (acc[mt][nt][r] - mean) * rstd * ga[nt] + be[nt] +
                        x[(size_t)m * D + c];
                }
            }
        }
    }
}

// ---------------- launch ----------------

extern "C" void kernel_launch(void* const* d_in, const int* in_sizes, int n_in,
                              void* d_out, int out_size, void* d_ws, size_t ws_size,
                              hipStream_t stream) {
    const float* x = (const float*)d_in[0];
    const int* eidx = (const int*)d_in[1];
    const float* W_l = (const float*)d_in[2];
    const float* b_l = (const float*)d_in[3];
    const float* W_r = (const float*)d_in[4];
    const float* gamma = (const float*)d_in[5];
    const float* beta = (const float*)d_in[6];
    float* out = (float*)d_out;

    const int N = in_sizes[0] / D;
    const int E = in_sizes[1] / 2;
    const int B1 = (N + 255) >> 8;  // 256-node buckets

    char* basep = (char*)d_ws;
    size_t off = 0;
    auto take = [&](size_t bytes) -> void* {
        void* r = basep + off;
        off += (bytes + 255) & ~(size_t)255;
        return r;
    };
    bf16_t* Agg = (bf16_t*)take((size_t)N * D * sizeof(bf16_t));       // 51.2 MB
    unsigned int* Xq = (unsigned int*)take((size_t)N * (D / 4) * 4);   // 25.6 MB
    int* edge_src = (int*)take((size_t)E * sizeof(int));               // 12.8 MB
    bf16_t* Wcat = (bf16_t*)take((size_t)D * KDIM * sizeof(bf16_t));
    int* row_ptr = (int*)take((size_t)(N + 1) * sizeof(int));
    int* bcur = (int*)take((size_t)B1 * 16 * sizeof(int));
    int* bbase = (int*)take((size_t)B1 * sizeof(int));
    // staging (B1*BCAP ints = 25.6MB) aliases Agg (51.2MB): consumed by
    // k_bucket strictly BEFORE k_aggregate writes Agg.
    int* staging = (int*)Agg;

    hipMemsetAsync(bcur, 0, (size_t)B1 * 16 * sizeof(int), stream);

    const int EB = (E + 255) / 256;

    k_scatter1<<<EB, 256, 0, stream>>>(eidx, bcur, staging, E);
    k_bbase<<<1, 512, 0, stream>>>(bcur, bbase, row_ptr, B1, N, E);
    k_bucket<<<B1, 256, 0, stream>>>(bcur, bbase, staging, edge_src, row_ptr, N);

    k_convx<<<(N * (D / 8) + 255) / 256, 256, 0, stream>>>(x, Xq, N * (D / 8));
    k_convw<<<(D * KDIM / 4 + 255) / 256, 256, 0, stream>>>(W_l, W_r, Wcat);

    k_aggregate<<<(N + 3) / 4, 256, 0, stream>>>(row_ptr, edge_src, Xq, Agg, N);

    k_gemm<<<(N + MTILE - 1) / MTILE, 256, 0, stream>>>(Agg, Wcat, x, b_l, gamma,
                                                        beta, out, N);
}

// Round 5
// 422.799 us; speedup vs baseline: 1.8229x; 1.8229x over previous
//
#include <hip/hip_runtime.h>

#define D 256
#define KDIM 512
#define BCAP 16384  // per-bucket staging capacity (avg fill 8184 for E=3.2M, B1=391)
#define BM 128
#define BK 32
#define NT 16  // KDIM / BK

typedef __bf16 bf16_t;
typedef bf16_t bf16x8 __attribute__((ext_vector_type(8)));
typedef bf16_t bf16x4 __attribute__((ext_vector_type(4)));
typedef float f32x4_t __attribute__((ext_vector_type(4)));
typedef float f32x2_t __attribute__((ext_vector_type(2)));

// async global->LDS, 16B/lane; LDS dest is wave-uniform base + lane*16
__device__ __forceinline__ void async_cp16(const void* g, void* l) {
    __builtin_amdgcn_global_load_lds(
        (const __attribute__((address_space(1))) unsigned int*)g,
        (__attribute__((address_space(3))) unsigned int*)l, 16, 0, 0);
}

// ---------------- CSR build (bucketed, no global hist) ----------------

// pass 1: coarse scatter into 256-node buckets; packed word = (dst&255)<<24 | src
__global__ __launch_bounds__(256) void k_scatter1(const int* __restrict__ eidx,
                                                  int* __restrict__ bcur,
                                                  int* __restrict__ staging, int E) {
    int e = blockIdx.x * 256 + threadIdx.x;
    if (e >= E) return;
    int s = eidx[e];
    int d = eidx[E + e];
    int b = d >> 8;
    int pos = atomicAdd(&bcur[b * 16], 1);  // cursors padded 1/line
    staging[(size_t)b * BCAP + pos] = ((d & 255) << 24) | s;  // s < 2^24
}

// scan of bucket counts -> bucket base offsets (B1 <= 512)
__global__ __launch_bounds__(512) void k_bbase(const int* __restrict__ bcur,
                                               int* __restrict__ bbase,
                                               int* __restrict__ row_ptr,
                                               int B1, int N, int E) {
    __shared__ int sm[512];
    int t = threadIdx.x;
    int v = (t < B1) ? bcur[t * 16] : 0;
    sm[t] = v;
    __syncthreads();
    for (int off = 1; off < 512; off <<= 1) {
        int u = (t >= off) ? sm[t - off] : 0;
        __syncthreads();
        sm[t] += u;
        __syncthreads();
    }
    if (t < B1) bbase[t] = sm[t] - v;  // exclusive
    if (t == 0) row_ptr[N] = E;
}

// pass 2: per-bucket hist + scan + counting-sort; emits row_ptr AND edge_src
__global__ __launch_bounds__(256) void k_bucket(const int* __restrict__ bcur,
                                                const int* __restrict__ bbase,
                                                const int* __restrict__ staging,
                                                int* __restrict__ edge_src,
                                                int* __restrict__ row_ptr, int N) {
    __shared__ int lhist[256];
    __shared__ int lscan[256];
    __shared__ int lcur[256];
    int b = blockIdx.x, t = threadIdx.x;
    int node_base = b << 8;
    int nn = N - node_base;
    if (nn > 256) nn = 256;
    int cnt = bcur[b * 16];
    int base = bbase[b];
    const int* stg = staging + (size_t)b * BCAP;

    lhist[t] = 0;
    __syncthreads();
    for (int i = t; i < cnt; i += 256)
        atomicAdd(&lhist[((unsigned)stg[i]) >> 24], 1);
    __syncthreads();
    int v = lhist[t];
    lscan[t] = v;
    __syncthreads();
    for (int off = 1; off < 256; off <<= 1) {
        int u = (t >= off) ? lscan[t - off] : 0;
        __syncthreads();
        lscan[t] += u;
        __syncthreads();
    }
    int excl = lscan[t] - v;
    if (t < nn) row_ptr[node_base + t] = base + excl;
    lscan[t] = excl;
    lcur[t] = 0;
    __syncthreads();
    for (int i = t; i < cnt; i += 256) {
        int w = stg[i];
        int ln = ((unsigned)w) >> 24;
        int src = w & 0xFFFFFF;
        int pos = base + lscan[ln] + atomicAdd(&lcur[ln], 1);
        edge_src[pos] = src;
    }
}

// ---------------- conversions ----------------

// x (f32) -> Xq (fp8 e4m3, packed 4/dword) — gather table for aggregation
__global__ __launch_bounds__(256) void k_convx(const float* __restrict__ x,
                                               unsigned int* __restrict__ Xq,
                                               int total8) {
    int i = blockIdx.x * 256 + threadIdx.x;  // one thread = 8 elems
    if (i >= total8) return;
    float4 v0 = *(const float4*)(x + (size_t)i * 8);
    float4 v1 = *(const float4*)(x + (size_t)i * 8 + 4);
    int w0 = 0, w1 = 0;
    w0 = __builtin_amdgcn_cvt_pk_fp8_f32(v0.x, v0.y, w0, false);
    w0 = __builtin_amdgcn_cvt_pk_fp8_f32(v0.z, v0.w, w0, true);
    w1 = __builtin_amdgcn_cvt_pk_fp8_f32(v1.x, v1.y, w1, false);
    w1 = __builtin_amdgcn_cvt_pk_fp8_f32(v1.z, v1.w, w1, true);
    uint2 o = {(unsigned)w0, (unsigned)w1};
    *(uint2*)(Xq + (size_t)i * 2) = o;
}

// Wcat [256][512] bf16: [:,0:256]=W_l, [:,256:512]=W_r
__global__ __launch_bounds__(256) void k_convw(const float* __restrict__ Wl,
                                               const float* __restrict__ Wr,
                                               bf16_t* __restrict__ Wcat) {
    int i = blockIdx.x * 256 + threadIdx.x;
    if (i >= D * KDIM / 4) return;
    int o = i * 4;
    int j = o >> 9;
    int k = o & 511;
    const float* src = (k < D) ? (Wl + (size_t)j * D + k)
                               : (Wr + (size_t)j * D + (k - D));
    float4 v = *(const float4*)src;
    bf16x4 ov = {(bf16_t)v.x, (bf16_t)v.y, (bf16_t)v.z, (bf16_t)v.w};
    *(bf16x4*)(Wcat + o) = ov;
}

// ------- aggregation: one wave per node, 4 fp8 rows per load instruction ----

__global__ __launch_bounds__(256) void k_aggregate(const int* __restrict__ row_ptr,
                                                   const int* __restrict__ edge_src,
                                                   const unsigned int* __restrict__ Xq,
                                                   bf16_t* __restrict__ Agg, int N) {
    int wv = threadIdx.x >> 6;
    int lane = threadIdx.x & 63;
    int node = blockIdx.x * 4 + wv;
    if (node >= N) return;
    int g = lane >> 4;       // row group 0..3
    int c = lane & 15;       // 16-fp8 column chunk
    int beg = row_ptr[node];
    int end = row_ptr[node + 1];

    float acc[16];
#pragma unroll
    for (int k = 0; k < 16; k++) acc[k] = 0.f;

#define ACC4(w, bidx)                                            \
    {                                                            \
        f32x2_t lo = __builtin_amdgcn_cvt_pk_f32_fp8((w), false);\
        f32x2_t hi = __builtin_amdgcn_cvt_pk_f32_fp8((w), true); \
        acc[(bidx) + 0] += lo[0];                                \
        acc[(bidx) + 1] += lo[1];                                \
        acc[(bidx) + 2] += hi[0];                                \
        acc[(bidx) + 3] += hi[1];                                \
    }

    for (int j = beg; j < end; j += 8) {
        int j0 = j + g, j1 = j + 4 + g;
        bool ok0 = j0 < end, ok1 = j1 < end;
        int s0 = edge_src[ok0 ? j0 : beg];
        int s1 = edge_src[ok1 ? j1 : beg];
        uint4 v0 = *(const uint4*)(Xq + (size_t)s0 * 64 + c * 4);
        uint4 v1 = *(const uint4*)(Xq + (size_t)s1 * 64 + c * 4);
        if (!ok0) { v0.x = 0; v0.y = 0; v0.z = 0; v0.w = 0; }
        if (!ok1) { v1.x = 0; v1.y = 0; v1.z = 0; v1.w = 0; }
        ACC4(v0.x, 0) ACC4(v0.y, 4) ACC4(v0.z, 8) ACC4(v0.w, 12)
        ACC4(v1.x, 0) ACC4(v1.y, 4) ACC4(v1.z, 8) ACC4(v1.w, 12)
    }
#undef ACC4

#pragma unroll
    for (int k = 0; k < 16; k++) {
        acc[k] += __shfl_xor(acc[k], 16, 64);
        acc[k] += __shfl_xor(acc[k], 32, 64);
    }
    int dg = end - beg;
    float inv = 1.0f / (float)(dg > 0 ? dg : 1);
    if (g == 0) {  // lanes 0..15 write 32B each = full 512B row
        bf16x8 o0 = {(bf16_t)(acc[0] * inv), (bf16_t)(acc[1] * inv),
                     (bf16_t)(acc[2] * inv), (bf16_t)(acc[3] * inv),
                     (bf16_t)(acc[4] * inv), (bf16_t)(acc[5] * inv),
                     (bf16_t)(acc[6] * inv), (bf16_t)(acc[7] * inv)};
        bf16x8 o1 = {(bf16_t)(acc[8] * inv), (bf16_t)(acc[9] * inv),
                     (bf16_t)(acc[10] * inv), (bf16_t)(acc[11] * inv),
                     (bf16_t)(acc[12] * inv), (bf16_t)(acc[13] * inv),
                     (bf16_t)(acc[14] * inv), (bf16_t)(acc[15] * inv)};
        *(bf16x8*)(Agg + (size_t)node * D + c * 16) = o0;
        *(bf16x8*)(Agg + (size_t)node * D + c * 16 + 8) = o1;
    }
}

// ------- GEMM: m97-style LDS double-buffer; fused GELU+LN+residual ---------
// 512 thr = 8 waves (2M x 4N); block tile 128 x 256; BK=32; K=512.
// A half-1 from Agg (bf16, global_load_lds); A half-2 from x (f32, reg+cvt);
// B from Wcat (global_load_lds). 16B-block XOR swizzle f(r)=(r^(r>>2))&3,
// applied rule-#21 style: linear DMA dest + inverse-swizzled global source
// + swizzled ds_read.

__global__ __launch_bounds__(512) void k_gemm(const bf16_t* __restrict__ Agg,
                                              const bf16_t* __restrict__ Wcat,
                                              const float* __restrict__ x,
                                              const float* __restrict__ b_l,
                                              const float* __restrict__ gamma,
                                              const float* __restrict__ beta,
                                              float* __restrict__ out, int M) {
    __shared__ __align__(16) bf16_t As[2][BM * BK];  // 8 KB x2
    __shared__ __align__(16) bf16_t Bs[2][D * BK];   // 16 KB x2
    __shared__ float sm_s[4][BM];
    __shared__ float sm_q[4][BM];

    const int tid = threadIdx.x;
    const int lane = tid & 63;
    const int wid = tid >> 6;
    const int lr = lane & 15;
    const int lh = lane >> 4;
    const int wm = wid >> 2;  // 0..1
    const int wn = wid & 3;   // 0..3
    const int row0 = blockIdx.x * BM;

    // --- staging constants ---
    const int sr = tid >> 2;                 // A row 0..127 / B row low
    const int sj = tid & 3;                  // 16B block in 64B row
    const int fA = (sr ^ (sr >> 2)) & 3;
    const int ar = (row0 + sr > M - 1) ? (M - 1) : (row0 + sr);
    const bf16_t* aggsrc = Agg + (size_t)ar * D + ((sj ^ fA) << 3);
    const float* xsrc = x + (size_t)ar * D + sj * 8;
    const int awr = sr * BK + ((sj ^ fA) << 3);  // swizzled ds_write slot
    const int rb1 = 128 + sr;
    const int fB1 = (rb1 ^ (rb1 >> 2)) & 3;
    const bf16_t* wsrc0 = Wcat + (size_t)sr * KDIM + ((sj ^ fA) << 3);
    const bf16_t* wsrc1 = Wcat + (size_t)rb1 * KDIM + ((sj ^ fB1) << 3);
    const int wbase8 = (tid & ~63) << 3;     // wave-uniform LDS element base

#define STAGE(buf, k0)                                                         \
    do {                                                                       \
        async_cp16(wsrc0 + (k0), &Bs[buf][wbase8]);                            \
        async_cp16(wsrc1 + (k0), &Bs[buf][4096 + wbase8]);                     \
        if ((k0) < D) {                                                        \
            async_cp16(aggsrc + (k0), &As[buf][wbase8]);                       \
        } else {                                                               \
            float4 u0 = *(const float4*)(xsrc + (k0) - D);                     \
            float4 u1 = *(const float4*)(xsrc + (k0) - D + 4);                 \
            bf16x8 v = {(bf16_t)u0.x, (bf16_t)u0.y, (bf16_t)u0.z,              \
                        (bf16_t)u0.w, (bf16_t)u1.x, (bf16_t)u1.y,              \
                        (bf16_t)u1.z, (bf16_t)u1.w};                           \
            *(bf16x8*)&As[buf][awr] = v;                                       \
        }                                                                      \
    } while (0)

    f32x4_t acc[4][4];
#pragma unroll
    for (int i = 0; i < 4; i++)
#pragma unroll
        for (int j = 0; j < 4; j++) acc[i][j] = (f32x4_t){0.f, 0.f, 0.f, 0.f};

    STAGE(0, 0);
    __syncthreads();

#pragma unroll
    for (int t = 0; t < NT; ++t) {
        const int cur = t & 1;
        if (t + 1 < NT) STAGE(cur ^ 1, (t + 1) * BK);

        bf16x8 a[4], b[4];
#pragma unroll
        for (int mt = 0; mt < 4; mt++) {
            int ra = wm * 64 + mt * 16 + lr;
            int blk = lh ^ ((ra ^ (ra >> 2)) & 3);
            a[mt] = *(const bf16x8*)&As[cur][ra * BK + (blk << 3)];
        }
#pragma unroll
        for (int nt = 0; nt < 4; nt++) {
            int rbn = wn * 64 + nt * 16 + lr;
            int blk = lh ^ ((rbn ^ (rbn >> 2)) & 3);
            b[nt] = *(const bf16x8*)&Bs[cur][rbn * BK + (blk << 3)];
        }
#pragma unroll
        for (int mt = 0; mt < 4; mt++)
#pragma unroll
            for (int nt = 0; nt < 4; nt++)
                acc[mt][nt] = __builtin_amdgcn_mfma_f32_16x16x32_bf16(
                    a[mt], b[nt], acc[mt][nt], 0, 0, 0);
        __syncthreads();
    }
#undef STAGE

    // ---- fused epilogue: bias + exact GELU + LayerNorm + residual ----
    // C/D layout: col = lane&15, row = (lane>>4)*4 + reg
    float bl[4], ga[4], be[4];
#pragma unroll
    for (int nt = 0; nt < 4; nt++) {
        int c = wn * 64 + nt * 16 + lr;
        bl[nt] = b_l[c];
        ga[nt] = gamma[c];
        be[nt] = beta[c];
    }

#pragma unroll
    for (int mt = 0; mt < 4; mt++) {
#pragma unroll
        for (int r = 0; r < 4; r++) {
            float s = 0.f, q = 0.f;
#pragma unroll
            for (int nt = 0; nt < 4; nt++) {
                float u = acc[mt][nt][r] + bl[nt];
                float ge = 0.5f * u * (1.0f + erff(u * 0.70710678118654752f));
                acc[mt][nt][r] = ge;
                s += ge;
                q += ge * ge;
            }
#pragma unroll
            for (int off = 8; off >= 1; off >>= 1) {
                s += __shfl_xor(s, off, 64);
                q += __shfl_xor(q, off, 64);
            }
            if (lr == 0) {
                int rl = wm * 64 + mt * 16 + lh * 4 + r;
                sm_s[wn][rl] = s;
                sm_q[wn][rl] = q;
            }
        }
    }
    __syncthreads();

#pragma unroll
    for (int mt = 0; mt < 4; mt++) {
#pragma unroll
        for (int r = 0; r < 4; r++) {
            int rl = wm * 64 + mt * 16 + lh * 4 + r;
            int m = row0 + rl;
            float S = sm_s[0][rl] + sm_s[1][rl] + sm_s[2][rl] + sm_s[3][rl];
            float Q = sm_q[0][rl] + sm_q[1][rl] + sm_q[2][rl] + sm_q[3][rl];
            float mean = S * (1.0f / 256.0f);
            float var = Q * (1.0f / 256.0f) - mean * mean;
            float rstd = rsqrtf(var + 1e-5f);
            if (m < M) {
#pragma unroll
                for (int nt = 0; nt < 4; nt++) {
                    int c = wn * 64 + nt * 16 + lr;
                    out[(size_t)m * D + c] =
                        (acc[mt][nt][r] - mean) * rstd * ga[nt] + be[nt] +
                        x[(size_t)m * D + c];
                }
            }
        }
    }
}

// ---------------- launch ----------------

extern "C" void kernel_launch(void* const* d_in, const int* in_sizes, int n_in,
                              void* d_out, int out_size, void* d_ws, size_t ws_size,
                              hipStream_t stream) {
    const float* x = (const float*)d_in[0];
    const int* eidx = (const int*)d_in[1];
    const float* W_l = (const float*)d_in[2];
    const float* b_l = (const float*)d_in[3];
    const float* W_r = (const float*)d_in[4];
    const float* gamma = (const float*)d_in[5];
    const float* beta = (const float*)d_in[6];
    float* out = (float*)d_out;

    const int N = in_sizes[0] / D;
    const int E = in_sizes[1] / 2;
    const int B1 = (N + 255) >> 8;  // 256-node buckets

    char* basep = (char*)d_ws;
    size_t off = 0;
    auto take = [&](size_t bytes) -> void* {
        void* r = basep + off;
        off += (bytes + 255) & ~(size_t)255;
        return r;
    };
    bf16_t* Agg = (bf16_t*)take((size_t)N * D * sizeof(bf16_t));       // 51.2 MB
    unsigned int* Xq = (unsigned int*)take((size_t)N * (D / 4) * 4);   // 25.6 MB
    int* edge_src = (int*)take((size_t)E * sizeof(int));               // 12.8 MB
    bf16_t* Wcat = (bf16_t*)take((size_t)D * KDIM * sizeof(bf16_t));
    int* row_ptr = (int*)take((size_t)(N + 1) * sizeof(int));
    int* bcur = (int*)take((size_t)B1 * 16 * sizeof(int));
    int* bbase = (int*)take((size_t)B1 * sizeof(int));
    // staging (B1*BCAP ints = 25.6MB) aliases Agg (51.2MB): consumed by
    // k_bucket strictly BEFORE k_aggregate writes Agg.
    int* staging = (int*)Agg;

    hipMemsetAsync(bcur, 0, (size_t)B1 * 16 * sizeof(int), stream);

    const int EB = (E + 255) / 256;

    k_scatter1<<<EB, 256, 0, stream>>>(eidx, bcur, staging, E);
    k_bbase<<<1, 512, 0, stream>>>(bcur, bbase, row_ptr, B1, N, E);
    k_bucket<<<B1, 256, 0, stream>>>(bcur, bbase, staging, edge_src, row_ptr, N);

    k_convx<<<(N * (D / 8) + 255) / 256, 256, 0, stream>>>(x, Xq, N * (D / 8));
    k_convw<<<(D * KDIM / 4 + 255) / 256, 256, 0, stream>>>(W_l, W_r, Wcat);

    k_aggregate<<<(N + 3) / 4, 256, 0, stream>>>(row_ptr, edge_src, Xq, Agg, N);

    k_gemm<<<(N + BM - 1) / BM, 512, 0, stream>>>(Agg, Wcat, x, b_l, gamma,
                                                  beta, out, N);
}

// Round 6
// 325.868 us; speedup vs baseline: 2.3652x; 1.2975x over previous
//
#include <hip/hip_runtime.h>

#define D 256
#define KDIM 512
#define BCAP 16384  // per-bucket staging capacity (avg fill 8192 for E=3.2M, B1=391)
#define EPB 8192    // edges per scatter block
#define BM 128
#define BK 32
#define NT 16  // KDIM / BK

typedef __bf16 bf16_t;
typedef bf16_t bf16x8 __attribute__((ext_vector_type(8)));
typedef bf16_t bf16x4 __attribute__((ext_vector_type(4)));
typedef float f32x4_t __attribute__((ext_vector_type(4)));
typedef float f32x2_t __attribute__((ext_vector_type(2)));

// async global->LDS, 16B/lane; LDS dest is wave-uniform base + lane*16
__device__ __forceinline__ void async_cp16(const void* g, void* l) {
    __builtin_amdgcn_global_load_lds(
        (const __attribute__((address_space(1))) unsigned int*)g,
        (__attribute__((address_space(3))) unsigned int*)l, 16, 0, 0);
}

// ---------------- CSR build (bucketed, block-aggregated scatter) -----------

// pass 1: per-block LDS histogram -> contiguous per-(block,bucket) runs.
// Each bucket receives a single ~EPB/B1-int contiguous run per block, so
// staging lines are assembled within one CU's L2 (write-amp ~1.1-1.8x, not 13x).
__global__ __launch_bounds__(256) void k_scatter1(const int* __restrict__ eidx,
                                                  int* __restrict__ bcur,
                                                  int* __restrict__ staging, int E) {
    __shared__ int lhist[512];
    __shared__ int lcur[512];
    __shared__ int gbase[512];
    const int t = threadIdx.x;
    const int e0 = blockIdx.x * EPB;
    int e1 = e0 + EPB;
    if (e1 > E) e1 = E;

    lhist[t] = 0;
    lhist[t + 256] = 0;
    lcur[t] = 0;
    lcur[t + 256] = 0;
    __syncthreads();

    for (int e = e0 + t; e < e1; e += 256) {
        int d = eidx[E + e];
        atomicAdd(&lhist[d >> 8], 1);
    }
    __syncthreads();

#pragma unroll
    for (int b = t; b < 512; b += 256) {
        int c = lhist[b];
        gbase[b] = (c > 0) ? atomicAdd(&bcur[b * 16], c) : 0;
    }
    __syncthreads();

    for (int e = e0 + t; e < e1; e += 256) {
        int s = eidx[e];
        int d = eidx[E + e];
        int b = d >> 8;
        int pos = gbase[b] + atomicAdd(&lcur[b], 1);
        staging[(size_t)b * BCAP + pos] = ((d & 255) << 24) | s;  // s < 2^24
    }
}

// scan of bucket counts -> bucket base offsets (B1 <= 512)
__global__ __launch_bounds__(512) void k_bbase(const int* __restrict__ bcur,
                                               int* __restrict__ bbase,
                                               int* __restrict__ row_ptr,
                                               int B1, int N, int E) {
    __shared__ int sm[512];
    int t = threadIdx.x;
    int v = (t < B1) ? bcur[t * 16] : 0;
    sm[t] = v;
    __syncthreads();
    for (int off = 1; off < 512; off <<= 1) {
        int u = (t >= off) ? sm[t - off] : 0;
        __syncthreads();
        sm[t] += u;
        __syncthreads();
    }
    if (t < B1) bbase[t] = sm[t] - v;  // exclusive
    if (t == 0) row_ptr[N] = E;
}

// pass 2: per-bucket hist + scan + counting-sort; emits row_ptr AND edge_src
__global__ __launch_bounds__(256) void k_bucket(const int* __restrict__ bcur,
                                                const int* __restrict__ bbase,
                                                const int* __restrict__ staging,
                                                int* __restrict__ edge_src,
                                                int* __restrict__ row_ptr, int N) {
    __shared__ int lhist[256];
    __shared__ int lscan[256];
    __shared__ int lcur[256];
    int b = blockIdx.x, t = threadIdx.x;
    int node_base = b << 8;
    int nn = N - node_base;
    if (nn > 256) nn = 256;
    int cnt = bcur[b * 16];
    int base = bbase[b];
    const int* stg = staging + (size_t)b * BCAP;

    lhist[t] = 0;
    __syncthreads();
    for (int i = t; i < cnt; i += 256)
        atomicAdd(&lhist[((unsigned)stg[i]) >> 24], 1);
    __syncthreads();
    int v = lhist[t];
    lscan[t] = v;
    __syncthreads();
    for (int off = 1; off < 256; off <<= 1) {
        int u = (t >= off) ? lscan[t - off] : 0;
        __syncthreads();
        lscan[t] += u;
        __syncthreads();
    }
    int excl = lscan[t] - v;
    if (t < nn) row_ptr[node_base + t] = base + excl;
    lscan[t] = excl;
    lcur[t] = 0;
    __syncthreads();
    for (int i = t; i < cnt; i += 256) {
        int w = stg[i];
        int ln = ((unsigned)w) >> 24;
        int src = w & 0xFFFFFF;
        int pos = base + lscan[ln] + atomicAdd(&lcur[ln], 1);
        edge_src[pos] = src;
    }
}

// ---------------- conversions ----------------

// x (f32) -> Xq (fp8 e4m3, packed 4/dword) — gather table for aggregation
__global__ __launch_bounds__(256) void k_convx(const float* __restrict__ x,
                                               unsigned int* __restrict__ Xq,
                                               int total8) {
    int i = blockIdx.x * 256 + threadIdx.x;  // one thread = 8 elems
    if (i >= total8) return;
    float4 v0 = *(const float4*)(x + (size_t)i * 8);
    float4 v1 = *(const float4*)(x + (size_t)i * 8 + 4);
    int w0 = 0, w1 = 0;
    w0 = __builtin_amdgcn_cvt_pk_fp8_f32(v0.x, v0.y, w0, false);
    w0 = __builtin_amdgcn_cvt_pk_fp8_f32(v0.z, v0.w, w0, true);
    w1 = __builtin_amdgcn_cvt_pk_fp8_f32(v1.x, v1.y, w1, false);
    w1 = __builtin_amdgcn_cvt_pk_fp8_f32(v1.z, v1.w, w1, true);
    uint2 o = {(unsigned)w0, (unsigned)w1};
    *(uint2*)(Xq + (size_t)i * 2) = o;
}

// Wcat [256][512] bf16: [:,0:256]=W_l, [:,256:512]=W_r
__global__ __launch_bounds__(256) void k_convw(const float* __restrict__ Wl,
                                               const float* __restrict__ Wr,
                                               bf16_t* __restrict__ Wcat) {
    int i = blockIdx.x * 256 + threadIdx.x;
    if (i >= D * KDIM / 4) return;
    int o = i * 4;
    int j = o >> 9;
    int k = o & 511;
    const float* src = (k < D) ? (Wl + (size_t)j * D + k)
                               : (Wr + (size_t)j * D + (k - D));
    float4 v = *(const float4*)src;
    bf16x4 ov = {(bf16_t)v.x, (bf16_t)v.y, (bf16_t)v.z, (bf16_t)v.w};
    *(bf16x4*)(Wcat + o) = ov;
}

// ------- aggregation: one wave per node, 4 fp8 rows per load instruction ----

__global__ __launch_bounds__(256) void k_aggregate(const int* __restrict__ row_ptr,
                                                   const int* __restrict__ edge_src,
                                                   const unsigned int* __restrict__ Xq,
                                                   bf16_t* __restrict__ Agg, int N) {
    int wv = threadIdx.x >> 6;
    int lane = threadIdx.x & 63;
    int node = blockIdx.x * 4 + wv;
    if (node >= N) return;
    int g = lane >> 4;       // row group 0..3
    int c = lane & 15;       // 16-fp8 column chunk
    int beg = row_ptr[node];
    int end = row_ptr[node + 1];

    float acc[16];
#pragma unroll
    for (int k = 0; k < 16; k++) acc[k] = 0.f;

#define ACC4(w, bidx)                                            \
    {                                                            \
        f32x2_t lo = __builtin_amdgcn_cvt_pk_f32_fp8((w), false);\
        f32x2_t hi = __builtin_amdgcn_cvt_pk_f32_fp8((w), true); \
        acc[(bidx) + 0] += lo[0];                                \
        acc[(bidx) + 1] += lo[1];                                \
        acc[(bidx) + 2] += hi[0];                                \
        acc[(bidx) + 3] += hi[1];                                \
    }

    for (int j = beg; j < end; j += 8) {
        int j0 = j + g, j1 = j + 4 + g;
        bool ok0 = j0 < end, ok1 = j1 < end;
        int s0 = edge_src[ok0 ? j0 : beg];
        int s1 = edge_src[ok1 ? j1 : beg];
        uint4 v0 = *(const uint4*)(Xq + (size_t)s0 * 64 + c * 4);
        uint4 v1 = *(const uint4*)(Xq + (size_t)s1 * 64 + c * 4);
        if (!ok0) { v0.x = 0; v0.y = 0; v0.z = 0; v0.w = 0; }
        if (!ok1) { v1.x = 0; v1.y = 0; v1.z = 0; v1.w = 0; }
        ACC4(v0.x, 0) ACC4(v0.y, 4) ACC4(v0.z, 8) ACC4(v0.w, 12)
        ACC4(v1.x, 0) ACC4(v1.y, 4) ACC4(v1.z, 8) ACC4(v1.w, 12)
    }
#undef ACC4

#pragma unroll
    for (int k = 0; k < 16; k++) {
        acc[k] += __shfl_xor(acc[k], 16, 64);
        acc[k] += __shfl_xor(acc[k], 32, 64);
    }
    int dg = end - beg;
    float inv = 1.0f / (float)(dg > 0 ? dg : 1);
    if (g == 0) {  // lanes 0..15 write 32B each = full 512B row
        bf16x8 o0 = {(bf16_t)(acc[0] * inv), (bf16_t)(acc[1] * inv),
                     (bf16_t)(acc[2] * inv), (bf16_t)(acc[3] * inv),
                     (bf16_t)(acc[4] * inv), (bf16_t)(acc[5] * inv),
                     (bf16_t)(acc[6] * inv), (bf16_t)(acc[7] * inv)};
        bf16x8 o1 = {(bf16_t)(acc[8] * inv), (bf16_t)(acc[9] * inv),
                     (bf16_t)(acc[10] * inv), (bf16_t)(acc[11] * inv),
                     (bf16_t)(acc[12] * inv), (bf16_t)(acc[13] * inv),
                     (bf16_t)(acc[14] * inv), (bf16_t)(acc[15] * inv)};
        *(bf16x8*)(Agg + (size_t)node * D + c * 16) = o0;
        *(bf16x8*)(Agg + (size_t)node * D + c * 16 + 8) = o1;
    }
}

// ------- GEMM: m97-style LDS double-buffer; fused GELU+LN+residual ---------
// 512 thr = 8 waves (2M x 4N); block tile 128 x 256; BK=32; K=512.
// A half-1 from Agg (bf16, global_load_lds); A half-2 from x (f32, reg+cvt);
// B from Wcat (global_load_lds). 16B-block XOR swizzle f(r)=(r^(r>>2))&3,
// applied rule-#21 style: linear DMA dest + inverse-swizzled global source
// + swizzled ds_read.

__global__ __launch_bounds__(512) void k_gemm(const bf16_t* __restrict__ Agg,
                                              const bf16_t* __restrict__ Wcat,
                                              const float* __restrict__ x,
                                              const float* __restrict__ b_l,
                                              const float* __restrict__ gamma,
                                              const float* __restrict__ beta,
                                              float* __restrict__ out, int M) {
    __shared__ __align__(16) bf16_t As[2][BM * BK];  // 8 KB x2
    __shared__ __align__(16) bf16_t Bs[2][D * BK];   // 16 KB x2
    __shared__ float sm_s[4][BM];
    __shared__ float sm_q[4][BM];

    const int tid = threadIdx.x;
    const int lane = tid & 63;
    const int wid = tid >> 6;
    const int lr = lane & 15;
    const int lh = lane >> 4;
    const int wm = wid >> 2;  // 0..1
    const int wn = wid & 3;   // 0..3
    const int row0 = blockIdx.x * BM;

    // --- staging constants ---
    const int sr = tid >> 2;                 // A row 0..127 / B row low
    const int sj = tid & 3;                  // 16B block in 64B row
    const int fA = (sr ^ (sr >> 2)) & 3;
    const int ar = (row0 + sr > M - 1) ? (M - 1) : (row0 + sr);
    const bf16_t* aggsrc = Agg + (size_t)ar * D + ((sj ^ fA) << 3);
    const float* xsrc = x + (size_t)ar * D + sj * 8;
    const int awr = sr * BK + ((sj ^ fA) << 3);  // swizzled ds_write slot
    const int rb1 = 128 + sr;
    const int fB1 = (rb1 ^ (rb1 >> 2)) & 3;
    const bf16_t* wsrc0 = Wcat + (size_t)sr * KDIM + ((sj ^ fA) << 3);
    const bf16_t* wsrc1 = Wcat + (size_t)rb1 * KDIM + ((sj ^ fB1) << 3);
    const int wbase8 = (tid & ~63) << 3;     // wave-uniform LDS element base

#define STAGE(buf, k0)                                                         \
    do {                                                                       \
        async_cp16(wsrc0 + (k0), &Bs[buf][wbase8]);                            \
        async_cp16(wsrc1 + (k0), &Bs[buf][4096 + wbase8]);                     \
        if ((k0) < D) {                                                        \
            async_cp16(aggsrc + (k0), &As[buf][wbase8]);                       \
        } else {                                                               \
            float4 u0 = *(const float4*)(xsrc + (k0) - D);                     \
            float4 u1 = *(const float4*)(xsrc + (k0) - D + 4);                 \
            bf16x8 v = {(bf16_t)u0.x, (bf16_t)u0.y, (bf16_t)u0.z,              \
                        (bf16_t)u0.w, (bf16_t)u1.x, (bf16_t)u1.y,              \
                        (bf16_t)u1.z, (bf16_t)u1.w};                           \
            *(bf16x8*)&As[buf][awr] = v;                                       \
        }                                                                      \
    } while (0)

    f32x4_t acc[4][4];
#pragma unroll
    for (int i = 0; i < 4; i++)
#pragma unroll
        for (int j = 0; j < 4; j++) acc[i][j] = (f32x4_t){0.f, 0.f, 0.f, 0.f};

    STAGE(0, 0);
    __syncthreads();

#pragma unroll
    for (int t = 0; t < NT; ++t) {
        const int cur = t & 1;
        if (t + 1 < NT) STAGE(cur ^ 1, (t + 1) * BK);

        bf16x8 a[4], b[4];
#pragma unroll
        for (int mt = 0; mt < 4; mt++) {
            int ra = wm * 64 + mt * 16 + lr;
            int blk = lh ^ ((ra ^ (ra >> 2)) & 3);
            a[mt] = *(const bf16x8*)&As[cur][ra * BK + (blk << 3)];
        }
#pragma unroll
        for (int nt = 0; nt < 4; nt++) {
            int rbn = wn * 64 + nt * 16 + lr;
            int blk = lh ^ ((rbn ^ (rbn >> 2)) & 3);
            b[nt] = *(const bf16x8*)&Bs[cur][rbn * BK + (blk << 3)];
        }
#pragma unroll
        for (int mt = 0; mt < 4; mt++)
#pragma unroll
            for (int nt = 0; nt < 4; nt++)
                acc[mt][nt] = __builtin_amdgcn_mfma_f32_16x16x32_bf16(
                    a[mt], b[nt], acc[mt][nt], 0, 0, 0);
        __syncthreads();
    }
#undef STAGE

    // ---- fused epilogue: bias + exact GELU + LayerNorm + residual ----
    // C/D layout: col = lane&15, row = (lane>>4)*4 + reg
    float bl[4], ga[4], be[4];
#pragma unroll
    for (int nt = 0; nt < 4; nt++) {
        int c = wn * 64 + nt * 16 + lr;
        bl[nt] = b_l[c];
        ga[nt] = gamma[c];
        be[nt] = beta[c];
    }

#pragma unroll
    for (int mt = 0; mt < 4; mt++) {
#pragma unroll
        for (int r = 0; r < 4; r++) {
            float s = 0.f, q = 0.f;
#pragma unroll
            for (int nt = 0; nt < 4; nt++) {
                float u = acc[mt][nt][r] + bl[nt];
                float ge = 0.5f * u * (1.0f + erff(u * 0.70710678118654752f));
                acc[mt][nt][r] = ge;
                s += ge;
                q += ge * ge;
            }
#pragma unroll
            for (int off = 8; off >= 1; off >>= 1) {
                s += __shfl_xor(s, off, 64);
                q += __shfl_xor(q, off, 64);
            }
            if (lr == 0) {
                int rl = wm * 64 + mt * 16 + lh * 4 + r;
                sm_s[wn][rl] = s;
                sm_q[wn][rl] = q;
            }
        }
    }
    __syncthreads();

#pragma unroll
    for (int mt = 0; mt < 4; mt++) {
#pragma unroll
        for (int r = 0; r < 4; r++) {
            int rl = wm * 64 + mt * 16 + lh * 4 + r;
            int m = row0 + rl;
            float S = sm_s[0][rl] + sm_s[1][rl] + sm_s[2][rl] + sm_s[3][rl];
            float Q = sm_q[0][rl] + sm_q[1][rl] + sm_q[2][rl] + sm_q[3][rl];
            float mean = S * (1.0f / 256.0f);
            float var = Q * (1.0f / 256.0f) - mean * mean;
            float rstd = rsqrtf(var + 1e-5f);
            if (m < M) {
#pragma unroll
                for (int nt = 0; nt < 4; nt++) {
                    int c = wn * 64 + nt * 16 + lr;
                    out[(size_t)m * D + c] =
                        (acc[mt][nt][r] - mean) * rstd * ga[nt] + be[nt] +
                        x[(size_t)m * D + c];
                }
            }
        }
    }
}

// ---------------- launch ----------------

extern "C" void kernel_launch(void* const* d_in, const int* in_sizes, int n_in,
                              void* d_out, int out_size, void* d_ws, size_t ws_size,
                              hipStream_t stream) {
    const float* x = (const float*)d_in[0];
    const int* eidx = (const int*)d_in[1];
    const float* W_l = (const float*)d_in[2];
    const float* b_l = (const float*)d_in[3];
    const float* W_r = (const float*)d_in[4];
    const float* gamma = (const float*)d_in[5];
    const float* beta = (const float*)d_in[6];
    float* out = (float*)d_out;

    const int N = in_sizes[0] / D;
    const int E = in_sizes[1] / 2;
    const int B1 = (N + 255) >> 8;  // 256-node buckets

    char* basep = (char*)d_ws;
    size_t off = 0;
    auto take = [&](size_t bytes) -> void* {
        void* r = basep + off;
        off += (bytes + 255) & ~(size_t)255;
        return r;
    };
    bf16_t* Agg = (bf16_t*)take((size_t)N * D * sizeof(bf16_t));       // 51.2 MB
    unsigned int* Xq = (unsigned int*)take((size_t)N * (D / 4) * 4);   // 25.6 MB
    int* edge_src = (int*)take((size_t)E * sizeof(int));               // 12.8 MB
    bf16_t* Wcat = (bf16_t*)take((size_t)D * KDIM * sizeof(bf16_t));
    int* row_ptr = (int*)take((size_t)(N + 1) * sizeof(int));
    int* bcur = (int*)take((size_t)B1 * 16 * sizeof(int));
    int* bbase = (int*)take((size_t)B1 * sizeof(int));
    // staging (B1*BCAP ints = 25.6MB) aliases Agg (51.2MB): consumed by
    // k_bucket strictly BEFORE k_aggregate writes Agg.
    int* staging = (int*)Agg;

    hipMemsetAsync(bcur, 0, (size_t)B1 * 16 * sizeof(int), stream);

    k_scatter1<<<(E + EPB - 1) / EPB, 256, 0, stream>>>(eidx, bcur, staging, E);
    k_bbase<<<1, 512, 0, stream>>>(bcur, bbase, row_ptr, B1, N, E);
    k_bucket<<<B1, 256, 0, stream>>>(bcur, bbase, staging, edge_src, row_ptr, N);

    k_convx<<<(N * (D / 8) + 255) / 256, 256, 0, stream>>>(x, Xq, N * (D / 8));
    k_convw<<<(D * KDIM / 4 + 255) / 256, 256, 0, stream>>>(W_l, W_r, Wcat);

    k_aggregate<<<(N + 3) / 4, 256, 0, stream>>>(row_ptr, edge_src, Xq, Agg, N);

    k_gemm<<<(N + BM - 1) / BM, 512, 0, stream>>>(Agg, Wcat, x, b_l, gamma,
                                                  beta, out, N);
}